// Round 1
// baseline (380.646 us; speedup 1.0000x reference)
//
#include <hip/hip_runtime.h>
#include <cmath>
#include <complex>
#include <algorithm>

// Sparse tensor product (e3nn 'uvu'): 128x0e+128x1o+128x2e (x) 1x0e+1x1o+1x2e -> 128x0e+128x1o+128x2e
// One thread per (z, u). CG coefficients computed host-side in fp64 (exact port of the
// reference su2_cg / real<->complex basis change / Frobenius normalization), alpha folded in,
// passed by value in kernarg (363 floats = 1452 B).

namespace {

constexpr int NPATH = 11;
constexpr int P_I1[NPATH] = {0,0,0,1,1,1,1,2,2,2,2};
constexpr int P_I2[NPATH] = {0,1,2,0,1,1,2,0,1,2,2};
constexpr int P_IO[NPATH] = {0,1,2,1,0,2,1,2,1,0,2};
constexpr int DIM_[3]  = {1,3,5};
constexpr int LOFF[3]  = {0,1,4};   // offsets of l-blocks inside a 9-float register set
constexpr int P_OFF[NPATH] = {0,1,10,35,44,53,98,143,168,213,238};
constexpr int CG_TOTAL = 363;

struct CGPack { float c[CG_TOTAL]; };

// ---------------- host-side e3nn Wigner 3j (real basis) ----------------

double fct(int n){ double r = 1.0; for(int i = 2; i <= n; ++i) r *= i; return r; }

double su2_cg(int j1,int m1,int j2,int m2,int j3,int m3){
  if (m3 != m1 + m2) return 0.0;
  int vmin = std::max(std::max(-j1 + j2 + m3, -j1 + m1), 0);
  int vmax = std::min(std::min(j2 + j3 + m1, j3 - j1 + j2), j3 + m3);
  double C = std::sqrt((2.0*j3 + 1.0) * fct(j3 + j1 - j2) * fct(j3 - j1 + j2) * fct(j1 + j2 - j3)
                       * fct(j3 + m3) * fct(j3 - m3)
                       / (fct(j1 + j2 + j3 + 1) * fct(j1 - m1) * fct(j1 + m1)
                          * fct(j2 - m2) * fct(j2 + m2)));
  double S = 0.0;
  for (int v = vmin; v <= vmax; ++v){
    double t = fct(j2 + j3 + m1 - v) * fct(j1 - m1 + v)
             / (fct(v) * fct(j3 - j1 + j2 - v) * fct(j3 + m3 - v) * fct(v + j1 - j2 - m3));
    S += (((v + j2 + m2) & 1) ? -1.0 : 1.0) * t;
  }
  return C * S;
}

void q_mat(int l, std::complex<double> q[5][5]){
  for (int a = 0; a < 5; ++a) for (int b = 0; b < 5; ++b) q[a][b] = 0.0;
  const double s = 1.0 / std::sqrt(2.0);
  for (int m = -l; m < 0; ++m){
    q[l+m][l-m] = s;                                   // col l+|m|
    q[l+m][l+m] = std::complex<double>(0.0, -s);       // col l-|m|
  }
  q[l][l] = 1.0;
  for (int m = 1; m <= l; ++m){
    double sg = (m & 1) ? -1.0 : 1.0;
    q[l+m][l+m] = sg * s;
    q[l+m][l-m] = std::complex<double>(0.0, sg * s);
  }
  std::complex<double> ph(1.0, 0.0);
  const std::complex<double> mi(0.0, -1.0);            // (-i)^l phase
  for (int t = 0; t < l; ++t) ph *= mi;
  for (int a = 0; a < 5; ++a) for (int b = 0; b < 5; ++b) q[a][b] *= ph;
}

void wigner3j(int l1, int l2, int l3, double scale, float* dst){
  const int n1 = 2*l1+1, n2 = 2*l2+1, n3 = 2*l3+1;
  std::complex<double> C[5][5][5];
  for (int a = 0; a < 5; ++a) for (int b = 0; b < 5; ++b) for (int c = 0; c < 5; ++c)
    C[a][b][c] = 0.0;
  for (int m1 = -l1; m1 <= l1; ++m1)
    for (int m2 = -l2; m2 <= l2; ++m2)
      for (int m3 = -l3; m3 <= l3; ++m3)
        C[l1+m1][l2+m2][l3+m3] = su2_cg(l1, m1, l2, m2, l3, m3);
  std::complex<double> Q1[5][5], Q2[5][5], Q3[5][5];
  q_mat(l1, Q1); q_mat(l2, Q2); q_mat(l3, Q3);
  // out[a,b,c] = sum_{i,k,n} Q1[i,a] * Q2[k,b] * conj(Q3[n,c]) * C[i,k,n]  (take real part)
  double R[5][5][5];
  double nrm = 0.0;
  for (int a = 0; a < n1; ++a)
    for (int b = 0; b < n2; ++b)
      for (int c = 0; c < n3; ++c){
        std::complex<double> s(0.0, 0.0);
        for (int i = 0; i < n1; ++i)
          for (int k = 0; k < n2; ++k)
            for (int n = 0; n < n3; ++n)
              s += Q1[i][a] * Q2[k][b] * std::conj(Q3[n][c]) * C[i][k][n];
        R[a][b][c] = s.real();
        nrm += s.real() * s.real();
      }
  nrm = std::sqrt(nrm);
  for (int a = 0; a < n1; ++a)
    for (int b = 0; b < n2; ++b)
      for (int c = 0; c < n3; ++c)
        dst[(a*n2 + b)*n3 + c] = (float)(scale * R[a][b][c] / nrm);
}

CGPack build_pack(){
  CGPack p;
  int npaths_to[3] = {0,0,0};
  for (int i = 0; i < NPATH; ++i) npaths_to[P_IO[i]]++;
  for (int i = 0; i < NPATH; ++i){
    double alpha = std::sqrt((double)DIM_[P_IO[i]] / (double)npaths_to[P_IO[i]]);
    wigner3j(P_I1[i], P_I2[i], P_IO[i], alpha, p.c + P_OFF[i]);
  }
  return p;
}

} // namespace

// ---------------- device kernel ----------------

__global__ __launch_bounds__(256) void tp_uvu_kernel(
    const float* __restrict__ x1, const float* __restrict__ x2,
    const float* __restrict__ w, float* __restrict__ out,
    int Z, CGPack cg)
{
  const int u    = threadIdx.x & 127;       // mul index 0..127
  const int zloc = threadIdx.x >> 7;        // 0 or 1
  const int z    = blockIdx.x * 2 + zloc;
  const bool active = (z < Z);

  __shared__ float s_x2[2][9];
  if (active && u < 9) s_x2[zloc][u] = x2[(size_t)z * 9 + u];
  __syncthreads();
  if (!active) return;

  float xv2[9];
  #pragma unroll
  for (int j = 0; j < 9; ++j) xv2[j] = s_x2[zloc][j];

  const float* x1z = x1 + (size_t)z * 1152;
  float in1[9];
  in1[0] = x1z[u];
  #pragma unroll
  for (int i = 0; i < 3; ++i) in1[1+i] = x1z[128 + u*3 + i];
  #pragma unroll
  for (int i = 0; i < 5; ++i) in1[4+i] = x1z[512 + u*5 + i];

  float o[9];
  #pragma unroll
  for (int k = 0; k < 9; ++k) o[k] = 0.0f;

  #pragma unroll
  for (int p = 0; p < NPATH; ++p){
    const float wv = w[p * 128 + u];
    const int l1 = P_I1[p], l2 = P_I2[p], lo = P_IO[p];
    const int d1 = DIM_[l1], d2 = DIM_[l2], dd = DIM_[lo];
    const int b1 = LOFF[l1], b2 = LOFF[l2], bo = LOFF[lo];
    #pragma unroll
    for (int i = 0; i < d1; ++i){
      #pragma unroll
      for (int j = 0; j < d2; ++j){
        const float t = wv * in1[b1 + i] * xv2[b2 + j];
        #pragma unroll
        for (int k = 0; k < dd; ++k)
          o[bo + k] = fmaf(t, cg.c[P_OFF[p] + (i*d2 + j)*dd + k], o[bo + k]);
      }
    }
  }

  float* oz = out + (size_t)z * 1152;
  oz[u] = o[0];
  #pragma unroll
  for (int k = 0; k < 3; ++k) oz[128 + u*3 + k] = o[1+k];
  #pragma unroll
  for (int k = 0; k < 5; ++k) oz[512 + u*5 + k] = o[4+k];
}

extern "C" void kernel_launch(void* const* d_in, const int* in_sizes, int n_in,
                              void* d_out, int out_size, void* d_ws, size_t ws_size,
                              hipStream_t stream)
{
  const float* x1 = (const float*)d_in[0];
  const float* x2 = (const float*)d_in[1];
  const float* w  = (const float*)d_in[2];
  float* out = (float*)d_out;
  const int Z = in_sizes[0] / 1152;

  CGPack pack = build_pack();   // host-only, identical every call (~µs)

  const int zpb = 2;
  dim3 grid((Z + zpb - 1) / zpb), block(128 * zpb);
  hipLaunchKernelGGL(tp_uvu_kernel, grid, block, 0, stream,
                     x1, x2, w, out, Z, pack);
}